// Round 3
// baseline (286.634 us; speedup 1.0000x reference)
//
#include <hip/hip_runtime.h>

// N=64, C=M=128, F=2048
//   scores[n,c,m] = sum_f X[n,c,f]*A[c,m,f];  W = softmax_m(scores)
//   out[n,c,f]    = sum_m W[n,c,m]*X[n,m,f]
// v3: v2 with the k_combine Xs staging-base fix (I*256, was I*128 — each
// global_load_lds covers 256 floats, bases must not overlap).

typedef __attribute__((ext_vector_type(8))) short bf16x8;
typedef __attribute__((ext_vector_type(4))) float f32x4;

#define PART_E (64 * 128 * 128)   // elements per K-partial
#define NP 8                      // K-split factor

static __device__ __forceinline__ unsigned f2bf_pk(float a, float b) {
    unsigned ua = __float_as_uint(a);
    unsigned ub = __float_as_uint(b);
    ua = (ua + 0x7FFFu + ((ua >> 16) & 1u)) >> 16;
    ub = (ub + 0x7FFFu + ((ub >> 16) & 1u)) >> 16;
    return ua | (ub << 16);
}
static __device__ __forceinline__ unsigned short f2bf1(float a) {
    unsigned ua = __float_as_uint(a);
    ua = (ua + 0x7FFFu + ((ua >> 16) & 1u)) >> 16;
    return (unsigned short)ua;
}
static __device__ __forceinline__ float bf2f(unsigned s) {
    return __uint_as_float(s << 16);
}
static __device__ __forceinline__ void gl_lds16(const void* g, void* l) {
    __builtin_amdgcn_global_load_lds((const __attribute__((address_space(1))) void*)g,
                                     (__attribute__((address_space(3))) void*)l, 16, 0, 0);
}
static __device__ __forceinline__ bf16x8 cvt8(float4 lo, float4 hi) {
    union { bf16x8 v; unsigned u[4]; } r;
    r.u[0] = f2bf_pk(lo.x, lo.y);
    r.u[1] = f2bf_pk(lo.z, lo.w);
    r.u[2] = f2bf_pk(hi.x, hi.y);
    r.u[3] = f2bf_pk(hi.z, hi.w);
    return r.v;
}

// ---------------- Kernel 1: partial scores (bf16 out) --------------------
// grid 1024 = c(128) x p(8); block 256; tile n64 x m128, K=256 (8 x BK32)
__global__ __launch_bounds__(256, 4) void k_scores(const float* __restrict__ X,
                                                   const float* __restrict__ A,
                                                   unsigned short* __restrict__ part) {
    __shared__ float Xs[64 * 32];    // 8 KB,  16B chunks swizzled: slot s holds chunk s^(r&7)
    __shared__ float As[128 * 32];   // 16 KB

    const int bx = blockIdx.x;
    const int c = bx >> 3;
    const int p = bx & 7;
    const int t = threadIdx.x;
    const int l = t & 63;
    const int w = t >> 6;
    const int l15 = l & 15;
    const int lg = l >> 4;
    const int wn = (w & 1) * 32;
    const int wm = (w >> 1) * 64;

    // staging lane constants: 8 chunks (16B) per 32-float row, 8 rows/inst
    const int lr = l >> 3;                 // sub-row 0..7
    const int lq = (l & 7) ^ lr;           // swizzled source chunk

    f32x4 acc[2][4];
#pragma unroll
    for (int i = 0; i < 2; ++i)
#pragma unroll
        for (int j = 0; j < 4; ++j) acc[i][j] = (f32x4)0.0f;

    const int s0 = (lg * 2) ^ (l15 & 7);
    const int s1 = (lg * 2 + 1) ^ (l15 & 7);

    for (int kb = 0; kb < 8; ++kb) {
        const int f = p * 256 + kb * 32 + lq * 4;
        // X tile 64x32: 8 insts, 2 per wave
#pragma unroll
        for (int ii = 0; ii < 2; ++ii) {
            const int I = 2 * w + ii;
            const int r = I * 8 + lr;
            gl_lds16(X + ((size_t)r * 128 + c) * 2048 + f, &Xs[I * 256]);
        }
        // A tile 128x32: 16 insts, 4 per wave
#pragma unroll
        for (int ii = 0; ii < 4; ++ii) {
            const int I = 4 * w + ii;
            const int r = I * 8 + lr;
            gl_lds16(A + ((size_t)c * 128 + r) * 2048 + f, &As[I * 256]);
        }
        __syncthreads();   // drains vmcnt: LDS tiles complete

        bf16x8 a[2], b[4];
#pragma unroll
        for (int i = 0; i < 2; ++i) {
            const float4* row = (const float4*)&Xs[(wn + 16 * i + l15) * 32];
            a[i] = cvt8(row[s0], row[s1]);
        }
#pragma unroll
        for (int j = 0; j < 4; ++j) {
            const float4* row = (const float4*)&As[(wm + 16 * j + l15) * 32];
            b[j] = cvt8(row[s0], row[s1]);
        }
#pragma unroll
        for (int i = 0; i < 2; ++i)
#pragma unroll
            for (int j = 0; j < 4; ++j)
                acc[i][j] = __builtin_amdgcn_mfma_f32_16x16x32_bf16(a[i], b[j], acc[i][j], 0, 0, 0);
        __syncthreads();   // all reads done before next overwrite
    }

    unsigned short* op = part + (size_t)p * PART_E;
#pragma unroll
    for (int i = 0; i < 2; ++i) {
        const int nb = wn + 16 * i + lg * 4;
#pragma unroll
        for (int j = 0; j < 4; ++j) {
            const int m = wm + 16 * j + l15;
#pragma unroll
            for (int r = 0; r < 4; ++r)
                op[((size_t)(nb + r) * 128 + c) * 128 + m] = f2bf1(acc[i][j][r]);
        }
    }
}

// ---------------- Kernel 2: sum bf16 partials + softmax -> W bf16 --------
// grid 2048 x 256: one wave per (n,c) row
__global__ __launch_bounds__(256) void k_softmax(const unsigned int* __restrict__ part,
                                                 unsigned int* __restrict__ Wout) {
    const int t = threadIdx.x;
    const int l = t & 63;
    const int row = blockIdx.x * 4 + (t >> 6);   // n*128 + c

    float v0 = 0.f, v1 = 0.f;
#pragma unroll
    for (int p = 0; p < NP; ++p) {
        unsigned u = part[(size_t)p * (PART_E / 2) + (size_t)row * 64 + l];
        v0 += bf2f(u & 0xFFFFu);
        v1 += bf2f(u >> 16);
    }
    float mx = fmaxf(v0, v1);
#pragma unroll
    for (int d = 1; d < 64; d <<= 1) mx = fmaxf(mx, __shfl_xor(mx, d, 64));
    float e0 = __expf(v0 - mx), e1 = __expf(v1 - mx);
    float sm = e0 + e1;
#pragma unroll
    for (int d = 1; d < 64; d <<= 1) sm += __shfl_xor(sm, d, 64);
    const float inv = 1.0f / sm;
    Wout[(size_t)row * 64 + l] = f2bf_pk(e0 * inv, e1 * inv);
}

// ---------------- Kernel 3: combine --------------------------------------
// grid 1024 = n(64) x f-tile(16); block 256; tile c128 x f128, K=m=128 (4 x 32)
__global__ __launch_bounds__(256, 3) void k_combine(const float* __restrict__ X,
                                                    const unsigned short* __restrict__ W,
                                                    float* __restrict__ out) {
    __shared__ unsigned short Wl[128 * 128]; // 32 KB bf16, chunks swizzled
    __shared__ float Xs[32 * 128];           // 16 KB fp32, row-major [m][f], unswizzled

    const int bx = blockIdx.x;
    const int n = bx >> 4;
    const int f0 = (bx & 15) * 128;
    const int t = threadIdx.x;
    const int l = t & 63;
    const int w = t >> 6;
    const int l15 = l & 15;
    const int lg = l >> 4;
    const int wc = (w >> 1) * 64;
    const int wf = (w & 1) * 64;

    // stage W[n] 128x128 bf16: rows of 16 chunks (16B), swizzled; 32 insts, 8/wave
    {
        const int lr = l >> 4;       // 0..3 rows per inst
        const int sl = l & 15;       // dest slot
#pragma unroll
        for (int ii = 0; ii < 8; ++ii) {
            const int I = 8 * w + ii;
            const int r = I * 4 + lr;
            const int q = (sl & 8) | ((sl ^ r) & 7);
            gl_lds16(W + (size_t)n * 16384 + r * 128 + q * 8, &Wl[I * 512]);
        }
    }

    f32x4 acc[4][4];
#pragma unroll
    for (int i = 0; i < 4; ++i)
#pragma unroll
        for (int j = 0; j < 4; ++j) acc[i][j] = (f32x4)0.0f;

    const int lr2 = l >> 5;          // 0..1 rows per inst
    const int q2 = l & 31;           // 16B chunk within 512B row

    for (int m0 = 0; m0 < 128; m0 += 32) {
        // stage X[n, m0:m0+32, f0:f0+128] fp32 row-major: 16 insts, 4/wave
        // each inst deposits 64 lanes x 16B = 256 floats = 2 rows
#pragma unroll
        for (int ii = 0; ii < 4; ++ii) {
            const int I = 4 * w + ii;
            const int r = I * 2 + lr2;
            gl_lds16(X + ((size_t)n * 128 + m0 + r) * 2048 + f0 + q2 * 4, &Xs[I * 256]);
        }
        __syncthreads();   // first iter also completes Wl

        bf16x8 a[4], b[4];
#pragma unroll
        for (int i = 0; i < 4; ++i) {
            const int cr = wc + 16 * i + l15;
            const int q = (m0 >> 3) + lg;
            const int s = (q & 8) | ((q ^ cr) & 7);
            a[i] = *(const bf16x8*)&Wl[cr * 128 + s * 8];
        }
#pragma unroll
        for (int j = 0; j < 4; ++j) {
            const float* col = &Xs[(lg * 8) * 128 + wf + 16 * j + l15];
            float v[8];
#pragma unroll
            for (int rr = 0; rr < 8; ++rr) v[rr] = col[rr * 128];
            union { bf16x8 bv; unsigned u[4]; } r_;
            r_.u[0] = f2bf_pk(v[0], v[1]);
            r_.u[1] = f2bf_pk(v[2], v[3]);
            r_.u[2] = f2bf_pk(v[4], v[5]);
            r_.u[3] = f2bf_pk(v[6], v[7]);
            b[j] = r_.bv;
        }
#pragma unroll
        for (int i = 0; i < 4; ++i)
#pragma unroll
            for (int j = 0; j < 4; ++j)
                acc[i][j] = __builtin_amdgcn_mfma_f32_16x16x32_bf16(a[i], b[j], acc[i][j], 0, 0, 0);
        __syncthreads();
    }

#pragma unroll
    for (int i = 0; i < 4; ++i) {
        const int c = wc + 16 * i + lg * 4;
#pragma unroll
        for (int j = 0; j < 4; ++j) {
            const int f = f0 + wf + 16 * j + l15;
            float* o = out + ((size_t)n * 128 + c) * 2048 + f;
#pragma unroll
            for (int r = 0; r < 4; ++r) o[(size_t)r * 2048] = acc[i][j][r];
        }
    }
}

extern "C" void kernel_launch(void* const* d_in, const int* in_sizes, int n_in,
                              void* d_out, int out_size, void* d_ws, size_t ws_size,
                              hipStream_t stream) {
    const float* X = (const float*)d_in[0];   // [64,128,2048]
    const float* A = (const float*)d_in[1];   // [128,128,2048]
    float* out = (float*)d_out;               // [64,128,2048]

    unsigned short* part = (unsigned short*)d_ws;              // 16 MiB bf16 partials
    unsigned short* Wb = part + (size_t)NP * PART_E;           // 2 MiB bf16 weights

    k_scores<<<dim3(1024), dim3(256), 0, stream>>>(X, A, part);
    k_softmax<<<dim3(2048), dim3(256), 0, stream>>>((const unsigned int*)part, (unsigned int*)Wb);
    k_combine<<<dim3(1024), dim3(256), 0, stream>>>(X, Wb, out);
}